// Round 4
// baseline (656.253 us; speedup 1.0000x reference)
//
#include <hip/hip_runtime.h>

#define SPATIAL 110592   // 48*48*48
#define CH 160
#define CPAD 168         // padded row length for W (LDS bank-even, 16B-aligned rows)
#define NTOT (CH*SPATIAL)
#define WELEM (CH*CPAD)  // 26880 ushort per weight matrix
#define W8 (WELEM/8)     // 3360 short8
#define NTILE 128
#define NBLK (SPATIAL/NTILE)   // 864 = 8*108
#define EPSV 1e-5f

typedef __attribute__((ext_vector_type(8))) short short8;
typedef __attribute__((ext_vector_type(4))) float f32x4;

#define MFMA(a,b,c) __builtin_amdgcn_mfma_f32_16x16x32_bf16((a),(b),(c),0,0,0)

__device__ __forceinline__ ushort f2bf(float f){
    union { float f; unsigned u; } v; v.f = f;
    return (ushort)((v.u + 0x7FFFu + ((v.u >> 16) & 1u)) >> 16);  // RNE
}
__device__ __forceinline__ float gelu_f(float v){
    return 0.5f*v*(1.0f + erff(v*0.70710678118654752f));
}

__device__ __forceinline__ void block_reduce2_atomic(float v0, float v1,
                                                     float* d0, float* d1){
    #pragma unroll
    for (int off = 32; off > 0; off >>= 1){
        v0 += __shfl_down(v0, off);
        v1 += __shfl_down(v1, off);
    }
    __shared__ float s0[4], s1[4];
    int wv = threadIdx.x >> 6, lane = threadIdx.x & 63;
    if (lane == 0){ s0[wv] = v0; s1[wv] = v1; }
    __syncthreads();
    if (threadIdx.x == 0){
        atomicAdd(d0, s0[0]+s0[1]+s0[2]+s0[3]);
        atomicAdd(d1, s1[0]+s1[1]+s1[2]+s1[3]);
    }
}

// W[o][c] fp32 -> bf16 padded row-major [160][CPAD]
__global__ __launch_bounds__(256)
void prep_weights(const float* __restrict__ w0, const float* __restrict__ w1,
                  const float* __restrict__ w2, const float* __restrict__ w3,
                  ushort* __restrict__ o0, ushort* __restrict__ o1,
                  ushort* __restrict__ o2, ushort* __restrict__ o3){
    const float* src[4] = {w0,w1,w2,w3};
    ushort*      dst[4] = {o0,o1,o2,o3};
    int m = blockIdx.y;
    int e = blockIdx.x*256 + threadIdx.x;
    if (e >= WELEM) return;
    int o = e / CPAD, c = e - o*CPAD;
    dst[m][e] = (c < CH) ? f2bf(src[m][o*CH + c]) : (ushort)0;
}

// conv1: h1[s][o] = b[o] + sum_c W[o][c]*x[c][s].  A = x (M=s), B = W (N=o).
// x is fp32 [C][S] read directly (coalesced scalar loads + inline bf16 cvt).
// out fp32 [S][C]. Barrier-free K-loop.
__global__ __launch_bounds__(256, 2)
void conv1_mfma(const float* __restrict__ x, const ushort* __restrict__ wp,
                const float* __restrict__ bias, float* __restrict__ h1,
                float* __restrict__ stats){
    __shared__ ushort WL[CH][CPAD];
    int t = threadIdx.x;
    for (int k = t; k < W8; k += 256) ((short8*)WL)[k] = ((const short8*)wp)[k];
    __syncthreads();

    int v = (blockIdx.x & 7)*108 + (blockIdx.x >> 3);
    int s_base = v*NTILE;
    int l = t & 63, wv = t >> 6, ln = l & 15, lg = l >> 4;
    int sA0 = s_base + wv*32 + ln;

    float br[10];
    #pragma unroll
    for (int nt = 0; nt < 10; ++nt) br[nt] = bias[nt*16 + ln];

    f32x4 acc[2][10];
    #pragma unroll
    for (int ms = 0; ms < 2; ++ms)
        #pragma unroll
        for (int nt = 0; nt < 10; ++nt) acc[ms][nt] = (f32x4)0.f;

    #pragma unroll
    for (int ks = 0; ks < 5; ++ks){
        short8 a[2];
        #pragma unroll
        for (int ms = 0; ms < 2; ++ms){
            const float* xp = x + (ks*32 + lg*8)*SPATIAL + sA0 + ms*16;
            #pragma unroll
            for (int i = 0; i < 8; ++i)
                a[ms][i] = (short)f2bf(xp[i*SPATIAL]);
        }
        #pragma unroll
        for (int nt = 0; nt < 10; ++nt){
            short8 b = *(const short8*)&WL[nt*16 + ln][ks*32 + lg*8];
            acc[0][nt] = MFMA(a[0], b, acc[0][nt]);
            acc[1][nt] = MFMA(a[1], b, acc[1][nt]);
        }
    }

    float lsum = 0.f, lsq = 0.f;
    int sO0 = s_base + wv*32 + lg*4;
    #pragma unroll
    for (int ms = 0; ms < 2; ++ms)
        #pragma unroll
        for (int nt = 0; nt < 10; ++nt)
            #pragma unroll
            for (int r = 0; r < 4; ++r){
                float val = acc[ms][nt][r] + br[nt];
                h1[(sO0 + ms*16 + r)*CH + nt*16 + ln] = val;
                lsum += val; lsq += val*val;
            }
    block_reduce2_atomic(lsum, lsq, stats, stats+1);
}

// GN1 affine + exact GELU: fp32 [S][C] -> bf16 [S][C]
__global__ __launch_bounds__(256)
void gn_gelu(const float* __restrict__ h, const float* __restrict__ g,
             const float* __restrict__ be, const float* __restrict__ stats,
             ushort* __restrict__ out){
    const float inv_n = 1.0f/(float)NTOT;
    float mu  = stats[0]*inv_n;
    float var = stats[1]*inv_n - mu*mu;
    float rs  = rsqrtf(var + EPSV);
    int nvec = NTOT/4;
    for (int i = blockIdx.x*256 + threadIdx.x; i < nvec; i += gridDim.x*256){
        int c0 = (i*4) % CH;                      // 160 % 4 == 0 -> aligned quads
        float4 gv = *(const float4*)&g[c0];
        float4 bv = *(const float4*)&be[c0];
        float4 x4 = ((const float4*)h)[i];
        ushort4 o;
        o.x = f2bf(gelu_f(fmaf(x4.x, rs*gv.x, bv.x - mu*rs*gv.x)));
        o.y = f2bf(gelu_f(fmaf(x4.y, rs*gv.y, bv.y - mu*rs*gv.y)));
        o.z = f2bf(gelu_f(fmaf(x4.z, rs*gv.z, bv.z - mu*rs*gv.z)));
        o.w = f2bf(gelu_f(fmaf(x4.w, rs*gv.w, bv.w - mu*rs*gv.w)));
        ((ushort4*)out)[i] = o;
    }
}

// three axial-shifted conv1x1 + gelu + sum, GN2 stats.
// A = shifted activations (per-lane shifted global short8 loads), B = W in LDS.
__global__ __launch_bounds__(256, 2)
void shift_conv3_mfma(const ushort* __restrict__ Ain,
                      const ushort* __restrict__ w21p, const float* __restrict__ b21,
                      const ushort* __restrict__ w22p, const float* __restrict__ b22,
                      const ushort* __restrict__ w23p, const float* __restrict__ b23,
                      ushort* __restrict__ out, float* __restrict__ stats){
    __shared__ ushort WL[CH][CPAD];
    int t = threadIdx.x;
    int v = (blockIdx.x & 7)*108 + (blockIdx.x >> 3);
    int s_base = v*NTILE;
    int l = t & 63, wv = t >> 6, ln = l & 15, lg = l >> 4;

    int srow[2], cd[2], chh[2], cww[2];
    #pragma unroll
    for (int ms = 0; ms < 2; ++ms){
        int s = s_base + wv*32 + ms*16 + ln;
        srow[ms] = s;
        cd[ms] = s / 2304; int rem = s - cd[ms]*2304;
        chh[ms] = rem / 48; cww[ms] = rem - chh[ms]*48;
    }

    f32x4 sum[2][10];
    #pragma unroll
    for (int ms = 0; ms < 2; ++ms)
        #pragma unroll
        for (int nt = 0; nt < 10; ++nt) sum[ms][nt] = (f32x4)0.f;

    auto branch = [&](const ushort* __restrict__ wp, const float* __restrict__ bias,
                      int AS, int c0, int c1){
        __syncthreads();
        for (int k = t; k < W8; k += 256) ((short8*)WL)[k] = ((const short8*)wp)[k];
        __syncthreads();

        float br[10];
        #pragma unroll
        for (int nt = 0; nt < 10; ++nt) br[nt] = bias[nt*16 + ln];

        int crd[2] = {c0, c1};
        f32x4 acc[2][10];
        #pragma unroll
        for (int ms = 0; ms < 2; ++ms)
            #pragma unroll
            for (int nt = 0; nt < 10; ++nt) acc[ms][nt] = (f32x4)0.f;

        #pragma unroll
        for (int ks = 0; ks < 5; ++ks){
            int sh = ks - 2;
            short8 a[2];
            #pragma unroll
            for (int ms = 0; ms < 2; ++ms){
                bool ok = ((unsigned)(crd[ms] - sh) < 48u);
                const short8* ap = (const short8*)
                    &Ain[(srow[ms] - sh*AS)*CH + ks*32 + lg*8];
                short8 av = (short8)0;
                if (ok) av = *ap;
                a[ms] = av;
            }
            #pragma unroll
            for (int nt = 0; nt < 10; ++nt){
                short8 b = *(const short8*)&WL[nt*16 + ln][ks*32 + lg*8];
                acc[0][nt] = MFMA(a[0], b, acc[0][nt]);
                acc[1][nt] = MFMA(a[1], b, acc[1][nt]);
            }
        }
        #pragma unroll
        for (int ms = 0; ms < 2; ++ms)
            #pragma unroll
            for (int nt = 0; nt < 10; ++nt)
                #pragma unroll
                for (int r = 0; r < 4; ++r)
                    sum[ms][nt][r] += gelu_f(acc[ms][nt][r] + br[nt]);
    };

    branch(w21p, b21, 2304, cd[0],  cd[1]);
    branch(w22p, b22, 48,   chh[0], chh[1]);
    branch(w23p, b23, 1,    cww[0], cww[1]);

    float lsum = 0.f, lsq = 0.f;
    int sO0 = s_base + wv*32 + lg*4;
    #pragma unroll
    for (int ms = 0; ms < 2; ++ms)
        #pragma unroll
        for (int nt = 0; nt < 10; ++nt)
            #pragma unroll
            for (int r = 0; r < 4; ++r){
                float val = sum[ms][nt][r];
                out[(sO0 + ms*16 + r)*CH + nt*16 + ln] = f2bf(val);
                lsum += val; lsq += val*val;
            }
    block_reduce2_atomic(lsum, lsq, stats+2, stats+3);
}

// fold GN2 affine into w3/b3: w3p[o][c] = w3[o][c]*a[c] (bf16 padded), b3p = b3 + w3·d
__global__ void fold_conv3(const float* __restrict__ w3, const float* __restrict__ b3,
                           const float* __restrict__ g2, const float* __restrict__ be2,
                           const float* __restrict__ stats,
                           ushort* __restrict__ w3p, float* __restrict__ b3p){
    __shared__ float a_sh[CH], d_sh[CH];
    const float inv_n = 1.0f/(float)NTOT;
    float mu  = stats[2]*inv_n;
    float var = stats[3]*inv_n - mu*mu;
    float rs  = rsqrtf(var + EPSV);
    for (int c = threadIdx.x; c < CH; c += blockDim.x){
        float a = rs*g2[c];
        a_sh[c] = a;
        d_sh[c] = be2[c] - mu*a;
    }
    __syncthreads();
    for (int e = threadIdx.x; e < WELEM; e += blockDim.x){
        int o = e / CPAD, c = e - o*CPAD;
        w3p[e] = (c < CH) ? f2bf(w3[o*CH + c]*a_sh[c]) : (ushort)0;
    }
    for (int o = threadIdx.x; o < CH; o += blockDim.x){
        float acc = b3[o];
        for (int c = 0; c < CH; ++c) acc += w3[o*CH + c]*d_sh[c];
        b3p[o] = acc;
    }
}

// conv3: out[o][s] = b[o] + sum_c W[o][c]*X[s][c].  A = W (M=o), B = X (N=s).
// out fp32 [C][S] (final layout). Barrier-free K-loop.
__global__ __launch_bounds__(256, 2)
void conv3_mfma(const ushort* __restrict__ X, const ushort* __restrict__ wp,
                const float* __restrict__ bias, float* __restrict__ out){
    __shared__ ushort WL[CH][CPAD];
    int t = threadIdx.x;
    for (int k = t; k < W8; k += 256) ((short8*)WL)[k] = ((const short8*)wp)[k];
    __syncthreads();

    int v = (blockIdx.x & 7)*108 + (blockIdx.x >> 3);
    int s_base = v*NTILE;
    int l = t & 63, wv = t >> 6, ln = l & 15, lg = l >> 4;
    int sB0 = s_base + wv*32 + ln;

    f32x4 acc[10][2];
    #pragma unroll
    for (int mt = 0; mt < 10; ++mt){ acc[mt][0] = (f32x4)0.f; acc[mt][1] = (f32x4)0.f; }

    #pragma unroll
    for (int ks = 0; ks < 5; ++ks){
        short8 b[2];
        #pragma unroll
        for (int ns = 0; ns < 2; ++ns)
            b[ns] = *(const short8*)&X[(sB0 + ns*16)*CH + ks*32 + lg*8];
        #pragma unroll
        for (int mt = 0; mt < 10; ++mt){
            short8 a = *(const short8*)&WL[mt*16 + ln][ks*32 + lg*8];
            acc[mt][0] = MFMA(a, b[0], acc[mt][0]);
            acc[mt][1] = MFMA(a, b[1], acc[mt][1]);
        }
    }

    #pragma unroll
    for (int mt = 0; mt < 10; ++mt){
        const float* bp = &bias[mt*16 + lg*4];
        #pragma unroll
        for (int ns = 0; ns < 2; ++ns)
            #pragma unroll
            for (int r = 0; r < 4; ++r)
                out[(mt*16 + lg*4 + r)*SPATIAL + sB0 + ns*16] = acc[mt][ns][r] + bp[r];
    }
}

extern "C" void kernel_launch(void* const* d_in, const int* in_sizes, int n_in,
                              void* d_out, int out_size, void* d_ws, size_t ws_size,
                              hipStream_t stream){
    const float* x   = (const float*)d_in[0];
    const float* w1  = (const float*)d_in[1];
    const float* b1  = (const float*)d_in[2];
    const float* g1  = (const float*)d_in[3];
    const float* be1 = (const float*)d_in[4];
    const float* w21 = (const float*)d_in[5];
    const float* b21 = (const float*)d_in[6];
    const float* w22 = (const float*)d_in[7];
    const float* b22 = (const float*)d_in[8];
    const float* w23 = (const float*)d_in[9];
    const float* b23 = (const float*)d_in[10];
    const float* g2  = (const float*)d_in[11];
    const float* be2 = (const float*)d_in[12];
    const float* w3  = (const float*)d_in[13];
    const float* b3  = (const float*)d_in[14];

    float*  buf1  = (float*)d_ws;                 // h1 fp32 [S][C]; later overlaid by buf3
    ushort* buf2  = (ushort*)(buf1 + NTOT);       // gelu(gn(h1)) bf16 [S][C]
    float*  stats = (float*)(buf2 + NTOT);        // 4 fp32 (pad 8)
    ushort* w1p   = (ushort*)(stats + 8);
    ushort* w21p  = w1p  + WELEM;
    ushort* w22p  = w21p + WELEM;
    ushort* w23p  = w22p + WELEM;
    ushort* w3p   = w23p + WELEM;
    float*  b3p   = (float*)(w3p + WELEM);
    ushort* buf3  = (ushort*)buf1;                // h2 bf16 [S][C] overlays dead h1

    hipMemsetAsync(stats, 0, 4*sizeof(float), stream);

    dim3 blk(256);
    prep_weights<<<dim3(WELEM/256, 4), blk, 0, stream>>>(
        w1, w21, w22, w23, w1p, w21p, w22p, w23p);
    conv1_mfma<<<dim3(NBLK), blk, 0, stream>>>(x, w1p, b1, buf1, stats);
    gn_gelu<<<dim3(2048), blk, 0, stream>>>(buf1, g1, be1, stats, buf2);
    shift_conv3_mfma<<<dim3(NBLK), blk, 0, stream>>>(
        buf2, w21p, b21, w22p, b22, w23p, b23, buf3, stats);
    fold_conv3<<<dim3(1), blk, 0, stream>>>(w3, b3, g2, be2, stats, w3p, b3p);
    conv3_mfma<<<dim3(NBLK), blk, 0, stream>>>(buf3, w3p, b3p, (float*)d_out);
}

// Round 6
// 531.371 us; speedup vs baseline: 1.2350x; 1.2350x over previous
//
#include <hip/hip_runtime.h>

#define SPATIAL 110592   // 48*48*48
#define CH 160
#define CPAD 168         // W row pad: 336B stride -> 2-way LDS aliasing (free), 16B aligned
#define NTOT (CH*SPATIAL)
#define WELEM (CH*CPAD)  // 26880 ushort per weight matrix
#define W8 (WELEM/8)     // 3360 short8
#define NTILE 256
#define NBLK (SPATIAL/NTILE)   // 432 = 8*54
#define EPSV 1e-5f

// chunked activation layout: plane kc = c>>5, elem = ((kc*SPATIAL)+s)*32 + (c&31)

typedef __attribute__((ext_vector_type(8))) short short8;
typedef __attribute__((ext_vector_type(4))) float f32x4;

#define MFMA(a,b,c) __builtin_amdgcn_mfma_f32_16x16x32_bf16((a),(b),(c),0,0,0)

__device__ __forceinline__ ushort f2bf(float f){
    union { float f; unsigned u; } v; v.f = f;
    return (ushort)((v.u + 0x7FFFu + ((v.u >> 16) & 1u)) >> 16);  // RNE
}
__device__ __forceinline__ float gelu_f(float v){
    return 0.5f*v*(1.0f + erff(v*0.70710678118654752f));
}

// block reduce for 512-thread blocks (8 waves)
__device__ __forceinline__ void block_reduce2_atomic8(float v0, float v1,
                                                      float* d0, float* d1){
    #pragma unroll
    for (int off = 32; off > 0; off >>= 1){
        v0 += __shfl_down(v0, off);
        v1 += __shfl_down(v1, off);
    }
    __shared__ float s0[8], s1[8];
    int wv = threadIdx.x >> 6, lane = threadIdx.x & 63;
    if (lane == 0){ s0[wv] = v0; s1[wv] = v1; }
    __syncthreads();
    if (threadIdx.x == 0){
        float a = 0.f, b = 0.f;
        #pragma unroll
        for (int i = 0; i < 8; ++i){ a += s0[i]; b += s1[i]; }
        atomicAdd(d0, a);
        atomicAdd(d1, b);
    }
}

// W[o][c] fp32 -> bf16 padded row-major [160][CPAD]
__global__ __launch_bounds__(256)
void prep_weights(const float* __restrict__ w0, const float* __restrict__ w1,
                  const float* __restrict__ w2, const float* __restrict__ w3,
                  ushort* __restrict__ o0, ushort* __restrict__ o1,
                  ushort* __restrict__ o2, ushort* __restrict__ o3){
    const float* src[4] = {w0,w1,w2,w3};
    ushort*      dst[4] = {o0,o1,o2,o3};
    int m = blockIdx.y;
    int e = blockIdx.x*256 + threadIdx.x;
    if (e >= WELEM) return;
    int o = e / CPAD, c = e - o*CPAD;
    dst[m][e] = (c < CH) ? f2bf(src[m][o*CH + c]) : (ushort)0;
}

// conv1: h1[s][o] = b[o] + sum_c W[o][c]*x[c][s].  A = x (M=s), B = W (N=o).
// x fp32 [C][S] direct coalesced loads + inline bf16 cvt. out: chunked fp32.
__global__ __launch_bounds__(512, 2)
void conv1_mfma(const float* __restrict__ x, const ushort* __restrict__ wp,
                const float* __restrict__ bias, float* __restrict__ h1c,
                float* __restrict__ stats){
    __shared__ ushort WL[CH][CPAD];
    int t = threadIdx.x;
    for (int k = t; k < W8; k += 512) ((short8*)WL)[k] = ((const short8*)wp)[k];
    __syncthreads();

    int v = (blockIdx.x & 7)*54 + (blockIdx.x >> 3);
    int s_base = v*NTILE;
    int l = t & 63, wv = t >> 6, ln = l & 15, lg = l >> 4;
    int sA0 = s_base + wv*32 + ln;

    f32x4 acc[2][10];
    #pragma unroll
    for (int ms = 0; ms < 2; ++ms)
        #pragma unroll
        for (int nt = 0; nt < 10; ++nt) acc[ms][nt] = (f32x4)0.f;

    #pragma unroll
    for (int ks = 0; ks < 5; ++ks){
        short8 a[2];
        #pragma unroll
        for (int ms = 0; ms < 2; ++ms){
            const float* xp = x + (ks*32 + lg*8)*SPATIAL + sA0 + ms*16;
            #pragma unroll
            for (int i = 0; i < 8; ++i)
                a[ms][i] = (short)f2bf(xp[i*SPATIAL]);
        }
        #pragma unroll
        for (int nt = 0; nt < 10; ++nt){
            short8 b = *(const short8*)&WL[nt*16 + ln][ks*32 + lg*8];
            acc[0][nt] = MFMA(a[0], b, acc[0][nt]);
            acc[1][nt] = MFMA(a[1], b, acc[1][nt]);
        }
    }

    float lsum = 0.f, lsq = 0.f;
    #pragma unroll
    for (int ms = 0; ms < 2; ++ms)
        #pragma unroll
        for (int nt = 0; nt < 10; ++nt){
            float bv = bias[nt*16 + ln];
            int kc = nt >> 1, ci = (nt & 1)*16 + ln;
            #pragma unroll
            for (int r = 0; r < 4; ++r){
                int srow = s_base + wv*32 + ms*16 + lg*4 + r;
                float val = acc[ms][nt][r] + bv;
                h1c[(kc*SPATIAL + srow)*32 + ci] = val;
                lsum += val; lsq += val*val;
            }
        }
    block_reduce2_atomic8(lsum, lsq, stats, stats+1);
}

// GN1 affine + exact GELU: chunked fp32 -> chunked bf16
__global__ __launch_bounds__(256)
void gn_gelu(const float* __restrict__ h, const float* __restrict__ g,
             const float* __restrict__ be, const float* __restrict__ stats,
             ushort* __restrict__ out){
    const float inv_n = 1.0f/(float)NTOT;
    float mu  = stats[0]*inv_n;
    float var = stats[1]*inv_n - mu*mu;
    float rs  = rsqrtf(var + EPSV);
    int nvec = NTOT/4;
    for (int i = blockIdx.x*256 + threadIdx.x; i < nvec; i += gridDim.x*256){
        int kc = (i >> 3) / SPATIAL;
        int c0 = kc*32 + (i & 7)*4;
        float4 gv = *(const float4*)&g[c0];
        float4 bv = *(const float4*)&be[c0];
        float4 x4 = ((const float4*)h)[i];
        ushort4 o;
        o.x = f2bf(gelu_f(fmaf(x4.x, rs*gv.x, bv.x - mu*rs*gv.x)));
        o.y = f2bf(gelu_f(fmaf(x4.y, rs*gv.y, bv.y - mu*rs*gv.y)));
        o.z = f2bf(gelu_f(fmaf(x4.z, rs*gv.z, bv.z - mu*rs*gv.z)));
        o.w = f2bf(gelu_f(fmaf(x4.w, rs*gv.w, bv.w - mu*rs*gv.w)));
        ((ushort4*)out)[i] = o;
    }
}

// three axial-shifted conv1x1 + gelu + sum, GN2 stats.
// ms-outer / branch-inner: live regs = sum[10][4] + acc[10][4] + a[5] ~ 115.
__global__ __launch_bounds__(512, 2)
void shift_conv3_mfma(const ushort* __restrict__ A2,
                      const ushort* __restrict__ w21p, const float* __restrict__ b21,
                      const ushort* __restrict__ w22p, const float* __restrict__ b22,
                      const ushort* __restrict__ w23p, const float* __restrict__ b23,
                      ushort* __restrict__ h2c, float* __restrict__ stats){
    __shared__ ushort WL[CH][CPAD];
    int t = threadIdx.x;
    int v = (blockIdx.x & 7)*54 + (blockIdx.x >> 3);
    int s_base = v*NTILE;
    int l = t & 63, wv = t >> 6, ln = l & 15, lg = l >> 4;

    const ushort* wps[3] = {w21p, w22p, w23p};
    const float*  bbs[3] = {b21, b22, b23};
    const int     ASv[3] = {2304, 48, 1};

    float lsum = 0.f, lsq = 0.f;

    #pragma unroll
    for (int ms = 0; ms < 2; ++ms){
        int srow = s_base + wv*32 + ms*16 + ln;
        int d   = srow / 2304;
        int rem = srow - d*2304;
        int hh  = rem / 48;
        int ww  = rem - hh*48;
        int crd[3] = {d, hh, ww};

        f32x4 sum[10];
        #pragma unroll
        for (int nt = 0; nt < 10; ++nt) sum[nt] = (f32x4)0.f;

        #pragma unroll
        for (int br = 0; br < 3; ++br){
            __syncthreads();
            for (int k = t; k < W8; k += 512)
                ((short8*)WL)[k] = ((const short8*)wps[br])[k];
            __syncthreads();

            short8 a[5];
            #pragma unroll
            for (int ks = 0; ks < 5; ++ks){
                int sh = ks - 2;
                bool ok = ((unsigned)(crd[br] - sh) < 48u);
                const short8* ap = (const short8*)
                    &A2[(ks*SPATIAL + srow - sh*ASv[br])*32 + lg*8];
                short8 av = (short8)0;
                if (ok) av = *ap;
                a[ks] = av;
            }

            f32x4 acc[10];
            #pragma unroll
            for (int nt = 0; nt < 10; ++nt) acc[nt] = (f32x4)0.f;

            #pragma unroll
            for (int ks = 0; ks < 5; ++ks)
                #pragma unroll
                for (int nt = 0; nt < 10; ++nt){
                    short8 b = *(const short8*)&WL[nt*16 + ln][ks*32 + lg*8];
                    acc[nt] = MFMA(a[ks], b, acc[nt]);
                }

            #pragma unroll
            for (int nt = 0; nt < 10; ++nt){
                float bv = bbs[br][nt*16 + ln];
                #pragma unroll
                for (int r = 0; r < 4; ++r)
                    sum[nt][r] += gelu_f(acc[nt][r] + bv);
            }
        }

        #pragma unroll
        for (int nt = 0; nt < 10; ++nt){
            int kc = nt >> 1, ci = (nt & 1)*16 + ln;
            #pragma unroll
            for (int r = 0; r < 4; ++r){
                int sr = s_base + wv*32 + ms*16 + lg*4 + r;
                float val = sum[nt][r];
                h2c[(kc*SPATIAL + sr)*32 + ci] = f2bf(val);
                lsum += val; lsq += val*val;
            }
        }
    }
    block_reduce2_atomic8(lsum, lsq, stats+2, stats+3);
}

// fold GN2 affine into w3/b3: w3p[o][c] = w3[o][c]*a[c] (bf16 padded), b3p = b3 + w3·d
__global__ void fold_conv3(const float* __restrict__ w3, const float* __restrict__ b3,
                           const float* __restrict__ g2, const float* __restrict__ be2,
                           const float* __restrict__ stats,
                           ushort* __restrict__ w3p, float* __restrict__ b3p){
    __shared__ float a_sh[CH], d_sh[CH];
    const float inv_n = 1.0f/(float)NTOT;
    float mu  = stats[2]*inv_n;
    float var = stats[3]*inv_n - mu*mu;
    float rs  = rsqrtf(var + EPSV);
    for (int c = threadIdx.x; c < CH; c += blockDim.x){
        float a = rs*g2[c];
        a_sh[c] = a;
        d_sh[c] = be2[c] - mu*a;
    }
    __syncthreads();
    for (int e = threadIdx.x; e < WELEM; e += blockDim.x){
        int o = e / CPAD, c = e - o*CPAD;
        w3p[e] = (c < CH) ? f2bf(w3[o*CH + c]*a_sh[c]) : (ushort)0;
    }
    for (int o = threadIdx.x; o < CH; o += blockDim.x){
        float acc = b3[o];
        for (int c = 0; c < CH; ++c) acc += w3[o*CH + c]*d_sh[c];
        b3p[o] = acc;
    }
}

// conv3: out[o][s] = b[o] + sum_c W[o][c]*X[s][c].  A = W (M=o), B = X chunked.
// out fp32 [C][S] (final layout).
__global__ __launch_bounds__(512, 2)
void conv3_mfma(const ushort* __restrict__ Xc, const ushort* __restrict__ wp,
                const float* __restrict__ bias, float* __restrict__ out){
    __shared__ ushort WL[CH][CPAD];
    int t = threadIdx.x;
    for (int k = t; k < W8; k += 512) ((short8*)WL)[k] = ((const short8*)wp)[k];
    __syncthreads();

    int v = (blockIdx.x & 7)*54 + (blockIdx.x >> 3);
    int s_base = v*NTILE;
    int l = t & 63, wv = t >> 6, ln = l & 15, lg = l >> 4;
    int sB0 = s_base + wv*32 + ln;

    f32x4 acc[10][2];
    #pragma unroll
    for (int mt = 0; mt < 10; ++mt){ acc[mt][0] = (f32x4)0.f; acc[mt][1] = (f32x4)0.f; }

    #pragma unroll
    for (int ks = 0; ks < 5; ++ks){
        short8 b[2];
        #pragma unroll
        for (int ns = 0; ns < 2; ++ns)
            b[ns] = *(const short8*)&Xc[(ks*SPATIAL + sB0 + ns*16)*32 + lg*8];
        #pragma unroll
        for (int mt = 0; mt < 10; ++mt){
            short8 a = *(const short8*)&WL[mt*16 + ln][ks*32 + lg*8];
            acc[mt][0] = MFMA(a, b[0], acc[mt][0]);
            acc[mt][1] = MFMA(a, b[1], acc[mt][1]);
        }
    }

    #pragma unroll
    for (int mt = 0; mt < 10; ++mt)
        #pragma unroll
        for (int r = 0; r < 4; ++r){
            float bv = bias[mt*16 + lg*4 + r];
            #pragma unroll
            for (int ns = 0; ns < 2; ++ns)
                out[(mt*16 + lg*4 + r)*SPATIAL + sB0 + ns*16] = acc[mt][ns][r] + bv;
        }
}

extern "C" void kernel_launch(void* const* d_in, const int* in_sizes, int n_in,
                              void* d_out, int out_size, void* d_ws, size_t ws_size,
                              hipStream_t stream){
    const float* x   = (const float*)d_in[0];
    const float* w1  = (const float*)d_in[1];
    const float* b1  = (const float*)d_in[2];
    const float* g1  = (const float*)d_in[3];
    const float* be1 = (const float*)d_in[4];
    const float* w21 = (const float*)d_in[5];
    const float* b21 = (const float*)d_in[6];
    const float* w22 = (const float*)d_in[7];
    const float* b22 = (const float*)d_in[8];
    const float* w23 = (const float*)d_in[9];
    const float* b23 = (const float*)d_in[10];
    const float* g2  = (const float*)d_in[11];
    const float* be2 = (const float*)d_in[12];
    const float* w3  = (const float*)d_in[13];
    const float* b3  = (const float*)d_in[14];

    float*  h1c   = (float*)d_ws;                 // chunked fp32 (NTOT); later h2c overlay
    ushort* A2    = (ushort*)(h1c + NTOT);        // chunked bf16 (NTOT)
    float*  stats = (float*)(A2 + NTOT);          // 4 fp32 (pad 8)
    ushort* w1p   = (ushort*)(stats + 8);
    ushort* w21p  = w1p  + WELEM;
    ushort* w22p  = w21p + WELEM;
    ushort* w23p  = w22p + WELEM;
    ushort* w3p   = w23p + WELEM;
    float*  b3p   = (float*)(w3p + WELEM);
    ushort* h2c   = (ushort*)h1c;                 // overlays dead h1c

    hipMemsetAsync(stats, 0, 4*sizeof(float), stream);

    prep_weights<<<dim3(WELEM/256, 4), dim3(256), 0, stream>>>(
        w1, w21, w22, w23, w1p, w21p, w22p, w23p);
    conv1_mfma<<<dim3(NBLK), dim3(512), 0, stream>>>(x, w1p, b1, h1c, stats);
    gn_gelu<<<dim3(2048), dim3(256), 0, stream>>>(h1c, g1, be1, stats, A2);
    shift_conv3_mfma<<<dim3(NBLK), dim3(512), 0, stream>>>(
        A2, w21p, b21, w22p, b22, w23p, b23, h2c, stats);
    fold_conv3<<<dim3(1), dim3(256), 0, stream>>>(w3, b3, g2, be2, stats, w3p, b3p);
    conv3_mfma<<<dim3(NBLK), dim3(512), 0, stream>>>(h2c, w3p, b3p, (float*)d_out);
}

// Round 7
// 396.917 us; speedup vs baseline: 1.6534x; 1.3387x over previous
//
#include <hip/hip_runtime.h>

#define SPATIAL 110592   // 48*48*48
#define CH 160
#define CPAD 168         // W row pad: 336B stride -> 2-way LDS aliasing (free), 16B aligned
#define NTOT (CH*SPATIAL)
#define WELEM (CH*CPAD)  // 26880 ushort per weight matrix
#define W8 (WELEM/8)     // 3360 short8
#define NTILE 256
#define NBLK (SPATIAL/NTILE)   // 432 = 8*54
#define EPSV 1e-5f

// chunked activation layout: plane kc = c>>5, elem = ((kc*SPATIAL)+s)*32 + (c&31)

typedef __attribute__((ext_vector_type(8))) short short8;
typedef __attribute__((ext_vector_type(4))) float f32x4;

#define MFMA(a,b,c) __builtin_amdgcn_mfma_f32_16x16x32_bf16((a),(b),(c),0,0,0)

__device__ __forceinline__ ushort f2bf(float f){
    union { float f; unsigned u; } v; v.f = f;
    return (ushort)((v.u + 0x7FFFu + ((v.u >> 16) & 1u)) >> 16);  // RNE
}
__device__ __forceinline__ float gelu_f(float v){
    return 0.5f*v*(1.0f + erff(v*0.70710678118654752f));
}

// block reduce for 512-thread blocks (8 waves)
__device__ __forceinline__ void block_reduce2_atomic8(float v0, float v1,
                                                      float* d0, float* d1){
    #pragma unroll
    for (int off = 32; off > 0; off >>= 1){
        v0 += __shfl_down(v0, off);
        v1 += __shfl_down(v1, off);
    }
    __shared__ float s0[8], s1[8];
    int wv = threadIdx.x >> 6, lane = threadIdx.x & 63;
    if (lane == 0){ s0[wv] = v0; s1[wv] = v1; }
    __syncthreads();
    if (threadIdx.x == 0){
        float a = 0.f, b = 0.f;
        #pragma unroll
        for (int i = 0; i < 8; ++i){ a += s0[i]; b += s1[i]; }
        atomicAdd(d0, a);
        atomicAdd(d1, b);
    }
}

// W[o][c] fp32 -> bf16 padded row-major [160][CPAD]
__global__ __launch_bounds__(256)
void prep_weights(const float* __restrict__ w0, const float* __restrict__ w1,
                  const float* __restrict__ w2, const float* __restrict__ w3,
                  ushort* __restrict__ o0, ushort* __restrict__ o1,
                  ushort* __restrict__ o2, ushort* __restrict__ o3){
    const float* src[4] = {w0,w1,w2,w3};
    ushort*      dst[4] = {o0,o1,o2,o3};
    int m = blockIdx.y;
    int e = blockIdx.x*256 + threadIdx.x;
    if (e >= WELEM) return;
    int o = e / CPAD, c = e - o*CPAD;
    dst[m][e] = (c < CH) ? f2bf(src[m][o*CH + c]) : (ushort)0;
}

// conv1: h1[s][o] = b[o] + sum_c W[o][c]*x[c][s].  A = x (M=s), B = W (N=o).
// ms-outer (unroll 1) keeps live set ~75 VGPR: acc[10](40) + a[5](20) + misc.
__global__ __launch_bounds__(512, 2)
void conv1_mfma(const float* __restrict__ x, const ushort* __restrict__ wp,
                const float* __restrict__ bias, float* __restrict__ h1c,
                float* __restrict__ stats){
    __shared__ ushort WL[CH][CPAD];
    int t = threadIdx.x;
    for (int k = t; k < W8; k += 512) ((short8*)WL)[k] = ((const short8*)wp)[k];
    __syncthreads();

    int v = (blockIdx.x & 7)*54 + (blockIdx.x >> 3);
    int s_base = v*NTILE;
    int l = t & 63, wv = t >> 6, ln = l & 15, lg = l >> 4;

    float lsum = 0.f, lsq = 0.f;

    #pragma unroll 1
    for (int ms = 0; ms < 2; ++ms){
        int sA = s_base + wv*32 + ms*16 + ln;     // A-frag row for this lane

        short8 a[5];
        #pragma unroll
        for (int ks = 0; ks < 5; ++ks){
            const float* xp = x + (ks*32 + lg*8)*SPATIAL + sA;
            #pragma unroll
            for (int i = 0; i < 8; ++i)
                a[ks][i] = (short)f2bf(xp[i*SPATIAL]);
        }

        f32x4 acc[10];
        #pragma unroll
        for (int nt = 0; nt < 10; ++nt) acc[nt] = (f32x4)0.f;

        #pragma unroll
        for (int ks = 0; ks < 5; ++ks)
            #pragma unroll
            for (int nt = 0; nt < 10; ++nt){
                short8 b = *(const short8*)&WL[nt*16 + ln][ks*32 + lg*8];
                acc[nt] = MFMA(a[ks], b, acc[nt]);
            }

        #pragma unroll
        for (int nt = 0; nt < 10; ++nt){
            float bv = bias[nt*16 + ln];
            int kc = nt >> 1, ci = (nt & 1)*16 + ln;
            #pragma unroll
            for (int r = 0; r < 4; ++r){
                int srow = s_base + wv*32 + ms*16 + lg*4 + r;
                float val = acc[nt][r] + bv;
                h1c[(kc*SPATIAL + srow)*32 + ci] = val;
                lsum += val; lsq += val*val;
            }
        }
    }
    block_reduce2_atomic8(lsum, lsq, stats, stats+1);
}

// GN1 affine + exact GELU: chunked fp32 -> chunked bf16
__global__ __launch_bounds__(256)
void gn_gelu(const float* __restrict__ h, const float* __restrict__ g,
             const float* __restrict__ be, const float* __restrict__ stats,
             ushort* __restrict__ out){
    const float inv_n = 1.0f/(float)NTOT;
    float mu  = stats[0]*inv_n;
    float var = stats[1]*inv_n - mu*mu;
    float rs  = rsqrtf(var + EPSV);
    int nvec = NTOT/4;
    for (int i = blockIdx.x*256 + threadIdx.x; i < nvec; i += gridDim.x*256){
        int kc = (i >> 3) / SPATIAL;
        int c0 = kc*32 + (i & 7)*4;
        float4 gv = *(const float4*)&g[c0];
        float4 bv = *(const float4*)&be[c0];
        float4 x4 = ((const float4*)h)[i];
        ushort4 o;
        o.x = f2bf(gelu_f(fmaf(x4.x, rs*gv.x, bv.x - mu*rs*gv.x)));
        o.y = f2bf(gelu_f(fmaf(x4.y, rs*gv.y, bv.y - mu*rs*gv.y)));
        o.z = f2bf(gelu_f(fmaf(x4.z, rs*gv.z, bv.z - mu*rs*gv.z)));
        o.w = f2bf(gelu_f(fmaf(x4.w, rs*gv.w, bv.w - mu*rs*gv.w)));
        ((ushort4*)out)[i] = o;
    }
}

// three axial-shifted conv1x1 + gelu + sum, GN2 stats.
// ms-outer (unroll 1) / br-inner (unroll 1), scalar selects (no runtime arrays):
// live set = sum[10](40) + acc[10](40) + a[5](20) + scalars ~= 110 <= 128.
__global__ __launch_bounds__(512, 2)
void shift_conv3_mfma(const ushort* __restrict__ A2,
                      const ushort* __restrict__ w21p, const float* __restrict__ b21,
                      const ushort* __restrict__ w22p, const float* __restrict__ b22,
                      const ushort* __restrict__ w23p, const float* __restrict__ b23,
                      ushort* __restrict__ h2c, float* __restrict__ stats){
    __shared__ ushort WL[CH][CPAD];
    int t = threadIdx.x;
    int v = (blockIdx.x & 7)*54 + (blockIdx.x >> 3);
    int s_base = v*NTILE;
    int l = t & 63, wv = t >> 6, ln = l & 15, lg = l >> 4;

    float lsum = 0.f, lsq = 0.f;

    #pragma unroll 1
    for (int ms = 0; ms < 2; ++ms){
        int srow = s_base + wv*32 + ms*16 + ln;
        int d   = srow / 2304;
        int rem = srow - d*2304;
        int hh  = rem / 48;
        int ww  = rem - hh*48;

        f32x4 sum[10];
        #pragma unroll
        for (int nt = 0; nt < 10; ++nt) sum[nt] = (f32x4)0.f;

        #pragma unroll 1
        for (int br = 0; br < 3; ++br){
            const ushort* wp = (br == 0) ? w21p : (br == 1) ? w22p : w23p;
            const float*  bb = (br == 0) ? b21  : (br == 1) ? b22  : b23;
            int AS  = (br == 0) ? 2304 : (br == 1) ? 48 : 1;
            int crd = (br == 0) ? d    : (br == 1) ? hh : ww;

            __syncthreads();
            for (int k = t; k < W8; k += 512)
                ((short8*)WL)[k] = ((const short8*)wp)[k];
            __syncthreads();

            short8 a[5];
            #pragma unroll
            for (int ks = 0; ks < 5; ++ks){
                int sh = ks - 2;
                bool ok = ((unsigned)(crd - sh) < 48u);
                const short8* ap = (const short8*)
                    &A2[(ks*SPATIAL + srow - sh*AS)*32 + lg*8];
                short8 av = (short8)0;
                if (ok) av = *ap;
                a[ks] = av;
            }

            f32x4 acc[10];
            #pragma unroll
            for (int nt = 0; nt < 10; ++nt) acc[nt] = (f32x4)0.f;

            #pragma unroll
            for (int ks = 0; ks < 5; ++ks)
                #pragma unroll
                for (int nt = 0; nt < 10; ++nt){
                    short8 b = *(const short8*)&WL[nt*16 + ln][ks*32 + lg*8];
                    acc[nt] = MFMA(a[ks], b, acc[nt]);
                }

            #pragma unroll
            for (int nt = 0; nt < 10; ++nt){
                float bv = bb[nt*16 + ln];
                #pragma unroll
                for (int r = 0; r < 4; ++r)
                    sum[nt][r] += gelu_f(acc[nt][r] + bv);
            }
        }

        #pragma unroll
        for (int nt = 0; nt < 10; ++nt){
            int kc = nt >> 1, ci = (nt & 1)*16 + ln;
            #pragma unroll
            for (int r = 0; r < 4; ++r){
                int sr = s_base + wv*32 + ms*16 + lg*4 + r;
                float val = sum[nt][r];
                h2c[(kc*SPATIAL + sr)*32 + ci] = f2bf(val);
                lsum += val; lsq += val*val;
            }
        }
    }
    block_reduce2_atomic8(lsum, lsq, stats+2, stats+3);
}

// fold GN2 affine into w3/b3: w3p[o][c] = w3[o][c]*a[c] (bf16 padded), b3p = b3 + w3·d
__global__ void fold_conv3(const float* __restrict__ w3, const float* __restrict__ b3,
                           const float* __restrict__ g2, const float* __restrict__ be2,
                           const float* __restrict__ stats,
                           ushort* __restrict__ w3p, float* __restrict__ b3p){
    __shared__ float a_sh[CH], d_sh[CH];
    const float inv_n = 1.0f/(float)NTOT;
    float mu  = stats[2]*inv_n;
    float var = stats[3]*inv_n - mu*mu;
    float rs  = rsqrtf(var + EPSV);
    for (int c = threadIdx.x; c < CH; c += blockDim.x){
        float a = rs*g2[c];
        a_sh[c] = a;
        d_sh[c] = be2[c] - mu*a;
    }
    __syncthreads();
    for (int e = threadIdx.x; e < WELEM; e += blockDim.x){
        int o = e / CPAD, c = e - o*CPAD;
        w3p[e] = (c < CH) ? f2bf(w3[o*CH + c]*a_sh[c]) : (ushort)0;
    }
    for (int o = threadIdx.x; o < CH; o += blockDim.x){
        float acc = b3[o];
        for (int c = 0; c < CH; ++c) acc += w3[o*CH + c]*d_sh[c];
        b3p[o] = acc;
    }
}

// conv3: out[o][s] = b[o] + sum_c W[o][c]*X[s][c].  A = W (M=o), B = X chunked.
// out fp32 [C][S] (final layout).
__global__ __launch_bounds__(512, 2)
void conv3_mfma(const ushort* __restrict__ Xc, const ushort* __restrict__ wp,
                const float* __restrict__ bias, float* __restrict__ out){
    __shared__ ushort WL[CH][CPAD];
    int t = threadIdx.x;
    for (int k = t; k < W8; k += 512) ((short8*)WL)[k] = ((const short8*)wp)[k];
    __syncthreads();

    int v = (blockIdx.x & 7)*54 + (blockIdx.x >> 3);
    int s_base = v*NTILE;
    int l = t & 63, wv = t >> 6, ln = l & 15, lg = l >> 4;
    int sB0 = s_base + wv*32 + ln;

    f32x4 acc[10][2];
    #pragma unroll
    for (int mt = 0; mt < 10; ++mt){ acc[mt][0] = (f32x4)0.f; acc[mt][1] = (f32x4)0.f; }

    #pragma unroll
    for (int ks = 0; ks < 5; ++ks){
        short8 b[2];
        #pragma unroll
        for (int ns = 0; ns < 2; ++ns)
            b[ns] = *(const short8*)&Xc[(ks*SPATIAL + sB0 + ns*16)*32 + lg*8];
        #pragma unroll
        for (int mt = 0; mt < 10; ++mt){
            short8 a = *(const short8*)&WL[mt*16 + ln][ks*32 + lg*8];
            acc[mt][0] = MFMA(a, b[0], acc[mt][0]);
            acc[mt][1] = MFMA(a, b[1], acc[mt][1]);
        }
    }

    #pragma unroll
    for (int mt = 0; mt < 10; ++mt)
        #pragma unroll
        for (int r = 0; r < 4; ++r){
            float bv = bias[mt*16 + lg*4 + r];
            #pragma unroll
            for (int ns = 0; ns < 2; ++ns)
                out[(mt*16 + lg*4 + r)*SPATIAL + sB0 + ns*16] = acc[mt][ns][r] + bv;
        }
}

extern "C" void kernel_launch(void* const* d_in, const int* in_sizes, int n_in,
                              void* d_out, int out_size, void* d_ws, size_t ws_size,
                              hipStream_t stream){
    const float* x   = (const float*)d_in[0];
    const float* w1  = (const float*)d_in[1];
    const float* b1  = (const float*)d_in[2];
    const float* g1  = (const float*)d_in[3];
    const float* be1 = (const float*)d_in[4];
    const float* w21 = (const float*)d_in[5];
    const float* b21 = (const float*)d_in[6];
    const float* w22 = (const float*)d_in[7];
    const float* b22 = (const float*)d_in[8];
    const float* w23 = (const float*)d_in[9];
    const float* b23 = (const float*)d_in[10];
    const float* g2  = (const float*)d_in[11];
    const float* be2 = (const float*)d_in[12];
    const float* w3  = (const float*)d_in[13];
    const float* b3  = (const float*)d_in[14];

    float*  h1c   = (float*)d_ws;                 // chunked fp32 (NTOT); later h2c overlay
    ushort* A2    = (ushort*)(h1c + NTOT);        // chunked bf16 (NTOT)
    float*  stats = (float*)(A2 + NTOT);          // 4 fp32 (pad 8)
    ushort* w1p   = (ushort*)(stats + 8);
    ushort* w21p  = w1p  + WELEM;
    ushort* w22p  = w21p + WELEM;
    ushort* w23p  = w22p + WELEM;
    ushort* w3p   = w23p + WELEM;
    float*  b3p   = (float*)(w3p + WELEM);
    ushort* h2c   = (ushort*)h1c;                 // overlays dead h1c

    hipMemsetAsync(stats, 0, 4*sizeof(float), stream);

    prep_weights<<<dim3(WELEM/256, 4), dim3(256), 0, stream>>>(
        w1, w21, w22, w23, w1p, w21p, w22p, w23p);
    conv1_mfma<<<dim3(NBLK), dim3(512), 0, stream>>>(x, w1p, b1, h1c, stats);
    gn_gelu<<<dim3(2048), dim3(256), 0, stream>>>(h1c, g1, be1, stats, A2);
    shift_conv3_mfma<<<dim3(NBLK), dim3(512), 0, stream>>>(
        A2, w21p, b21, w22p, b22, w23p, b23, h2c, stats);
    fold_conv3<<<dim3(1), dim3(256), 0, stream>>>(w3, b3, g2, be2, stats, w3p, b3p);
    conv3_mfma<<<dim3(NBLK), dim3(512), 0, stream>>>(h2c, w3p, b3p, (float*)d_out);
}